// Round 4
// baseline (2219.824 us; speedup 1.0000x reference)
//
#include <hip/hip_runtime.h>
#include <math.h>

#define BB 4
#define NN 4096
#define KNNK 16
#define DD 128
#define BN (BB*NN)

typedef __attribute__((ext_vector_type(8))) short short8;   // 8 bf16
typedef __attribute__((ext_vector_type(4))) float floatx4;  // MFMA acc

__device__ __forceinline__ short f2bf(float x) {
  unsigned u = __float_as_uint(x);
  unsigned r = (u + 0x7fffu + ((u >> 16) & 1u)) >> 16;
  return (short)r;
}

// ---------------------------------------------------------------------------
// mv16: acc[p] += sum_f A[p][f] * W[f*128 + t]  (A in LDS, wave-broadcast reads)
// ---------------------------------------------------------------------------
__device__ __forceinline__ void mv16(const float* __restrict__ Wcol,
                                     const float* __restrict__ A,
                                     float acc[16]) {
#pragma unroll 2
  for (int f4 = 0; f4 < 32; ++f4) {
    float w0 = Wcol[(4 * f4 + 0) * 128];
    float w1 = Wcol[(4 * f4 + 1) * 128];
    float w2 = Wcol[(4 * f4 + 2) * 128];
    float w3 = Wcol[(4 * f4 + 3) * 128];
#pragma unroll
    for (int p = 0; p < 16; ++p) {
      float4 a = *reinterpret_cast<const float4*>(A + p * 128 + 4 * f4);
      acc[p] = fmaf(a.w, w3, fmaf(a.z, w2, fmaf(a.y, w1, fmaf(a.x, w0, acc[p]))));
    }
  }
}

// ---------------------------------------------------------------------------
// KNN v2: one block per query (16384 blocks, 256 threads). Thread computes 16
// distances (exact reference formula), packs (mapped_d, idx) into one u64 so
// a single u64 compare reproduces top_k's (value, index) ordering. Branchless
// Batcher network sorts 16 keys in registers; 8-level LDS merge tree (shift-
// register merge, one barrier per level) reduces 256 sorted lists to top-16.
// ---------------------------------------------------------------------------
#define CE(i, j)                                   \
  {                                                \
    unsigned long long ki = v[i], kj = v[j];       \
    bool sw = kj < ki;                             \
    v[i] = sw ? kj : ki;                           \
    v[j] = sw ? ki : kj;                           \
  }

__global__ __launch_bounds__(256, 4) void knn_kernel(const float* __restrict__ xyz,
                                                     int* __restrict__ knn) {
  const int t = threadIdx.x;
  const int bn = blockIdx.x;
  const int b = bn >> 12;
  const int n = bn & 4095;
  const float* xb = xyz + (size_t)b * NN * 3;

  const float qx = xb[n * 3 + 0], qy = xb[n * 3 + 1], qz = xb[n * 3 + 2];
  const float qsq = __fadd_rn(__fadd_rn(__fmul_rn(qx, qx), __fmul_rn(qy, qy)),
                              __fmul_rn(qz, qz));

  __shared__ unsigned long long lists[256 * 16];  // 32 KB

  unsigned long long v[16];
#pragma unroll
  for (int j = 0; j < 16; ++j) {
    const int c = j * 256 + t;
    float cx = xb[c * 3 + 0], cy = xb[c * 3 + 1], cz = xb[c * 3 + 2];
    float csq = __fadd_rn(__fadd_rn(__fmul_rn(cx, cx), __fmul_rn(cy, cy)),
                          __fmul_rn(cz, cz));
    float dot = __fadd_rn(__fadd_rn(__fmul_rn(qx, cx), __fmul_rn(qy, cy)),
                          __fmul_rn(qz, cz));
    float d = __fadd_rn(__fsub_rn(qsq, __fmul_rn(2.0f, dot)), csq);
    unsigned u = __float_as_uint(d);
    u = (u & 0x80000000u) ? ~u : (u | 0x80000000u);  // monotone float->uint
    v[j] = ((unsigned long long)u << 32) | (unsigned)c;
  }

  // Batcher odd-even mergesort, 63 comparators, ascending
  CE(0, 1) CE(2, 3) CE(4, 5) CE(6, 7) CE(8, 9) CE(10, 11) CE(12, 13) CE(14, 15)
  CE(0, 2) CE(1, 3) CE(4, 6) CE(5, 7) CE(8, 10) CE(9, 11) CE(12, 14) CE(13, 15)
  CE(1, 2) CE(5, 6) CE(9, 10) CE(13, 14)
  CE(0, 4) CE(1, 5) CE(2, 6) CE(3, 7) CE(8, 12) CE(9, 13) CE(10, 14) CE(11, 15)
  CE(2, 4) CE(3, 5) CE(10, 12) CE(11, 13)
  CE(1, 2) CE(3, 4) CE(5, 6) CE(9, 10) CE(11, 12) CE(13, 14)
  CE(0, 8) CE(1, 9) CE(2, 10) CE(3, 11) CE(4, 12) CE(5, 13) CE(6, 14) CE(7, 15)
  CE(4, 8) CE(5, 9) CE(6, 10) CE(7, 11)
  CE(2, 4) CE(3, 5) CE(6, 8) CE(7, 9) CE(10, 12) CE(11, 13)
  CE(1, 2) CE(3, 4) CE(5, 6) CE(7, 8) CE(9, 10) CE(11, 12) CE(13, 14)

#pragma unroll
  for (int j = 0; j < 16; ++j) lists[t * 16 + j] = v[j];
  __syncthreads();

  // merge tree: 256 -> 1 sorted-16 lists. At each level, active thread t
  // merges its list with list t+stride; writes top-16 back to its own slot
  // (nobody else reads that slot at this level -> single barrier suffices).
#pragma unroll 1
  for (int lvl = 0; lvl < 8; ++lvl) {
    const int stride = 1 << lvl;
    const bool active = (t & (2 * stride - 1)) == 0;
    if (active) {
      unsigned long long A[16], B[16];
      const unsigned long long* pa = &lists[t * 16];
      const unsigned long long* pb = &lists[(t + stride) * 16];
#pragma unroll
      for (int j = 0; j < 16; ++j) A[j] = pa[j];
#pragma unroll
      for (int j = 0; j < 16; ++j) B[j] = pb[j];
      unsigned long long* po = &lists[t * 16];
#pragma unroll
      for (int k = 0; k < 16; ++k) {
        bool ta = A[0] <= B[0];
        po[k] = ta ? A[0] : B[0];
#pragma unroll
        for (int u = 0; u < 15; ++u) {
          A[u] = ta ? A[u + 1] : A[u];
          B[u] = ta ? B[u] : B[u + 1];
        }
      }
    }
    __syncthreads();
  }

  if (t < 16) knn[(size_t)bn * KNNK + t] = (int)(unsigned)(lists[t] & 0xffffffffu);
}
#undef CE

// ---------------------------------------------------------------------------
// Per-point MLP chain (unchanged from verified baseline)
// ---------------------------------------------------------------------------
__global__ __launch_bounds__(128, 2) void point_mlp_kernel(
    const float* __restrict__ xyz, const float* __restrict__ W0a,
    const float* __restrict__ b0a, const float* __restrict__ W0b,
    const float* __restrict__ b0b, const float* __restrict__ W1,
    const float* __restrict__ b1, const float* __restrict__ Wq,
    const float* __restrict__ Wk, const float* __restrict__ Wv,
    float* __restrict__ pre, float* __restrict__ qv, float* __restrict__ kv,
    float* __restrict__ vv) {
  const int t = threadIdx.x;
  const int g0 = blockIdx.x * 16;
  __shared__ float4 pool[2 * 512 + 16];
  float* bufA = (float*)pool;
  float* bufB = bufA + 2048;
  float* xs = bufB + 2048;  // [16][4]
  if (t < 48) {
    int p = t / 3, c = t % 3;
    xs[p * 4 + c] = xyz[(size_t)(g0 + p) * 3 + c];
  }
  __syncthreads();
  {
    float wa0 = W0a[t], wa1 = W0a[128 + t], wa2 = W0a[256 + t], ba = b0a[t];
#pragma unroll
    for (int p = 0; p < 16; ++p) {
      float v = fmaf(xs[p * 4 + 2], wa2,
                     fmaf(xs[p * 4 + 1], wa1, fmaf(xs[p * 4 + 0], wa0, ba)));
      bufA[p * 128 + t] = fmaxf(v, 0.f);
    }
  }
  __syncthreads();
  float acc[16];
  {
    float bb = b0b[t];
#pragma unroll
    for (int p = 0; p < 16; ++p) acc[p] = bb;
    mv16(W0b + t, bufA, acc);
#pragma unroll
    for (int p = 0; p < 16; ++p) {
      bufB[p * 128 + t] = acc[p];
      pre[(size_t)(g0 + p) * 128 + t] = acc[p];
    }
  }
  __syncthreads();
  {
    float bb = b1[t];
#pragma unroll
    for (int p = 0; p < 16; ++p) acc[p] = bb;
    mv16(W1 + t, bufB, acc);
#pragma unroll
    for (int p = 0; p < 16; ++p) bufA[p * 128 + t] = acc[p];
  }
  __syncthreads();
  {
#pragma unroll
    for (int p = 0; p < 16; ++p) acc[p] = 0.f;
    mv16(Wq + t, bufA, acc);
#pragma unroll
    for (int p = 0; p < 16; ++p) qv[(size_t)(g0 + p) * 128 + t] = acc[p];
  }
  {
#pragma unroll
    for (int p = 0; p < 16; ++p) acc[p] = 0.f;
    mv16(Wk + t, bufA, acc);
#pragma unroll
    for (int p = 0; p < 16; ++p) kv[(size_t)(g0 + p) * 128 + t] = acc[p];
  }
  {
#pragma unroll
    for (int p = 0; p < 16; ++p) acc[p] = 0.f;
    mv16(Wv + t, bufA, acc);
#pragma unroll
    for (int p = 0; p < 16; ++p) vv[(size_t)(g0 + p) * 128 + t] = acc[p];
  }
}

// ---------------------------------------------------------------------------
// Weight pre-swizzle: Wd2/Wg1/Wg2 (fp32 [k(128)][n(128)]) -> bf16 B-fragment
// order for mfma_f32_16x16x32_bf16: wsw[stage][nt][ks][lane][j],
// element = W[(ks*32 + (lane>>4)*8 + j)*128 + nt*16 + (lane&15)].
// ---------------------------------------------------------------------------
__global__ void swz_kernel(const float* __restrict__ Wd2,
                           const float* __restrict__ Wg1,
                           const float* __restrict__ Wg2,
                           short* __restrict__ wsw) {
  int t = blockIdx.x * 256 + threadIdx.x;  // [0, 6144): [stage][nt][ks][lane]
  if (t >= 3 * 2048) return;
  int stage = t / 2048;
  int rem = t % 2048;
  int nt = rem / 256;
  int ks = (rem % 256) / 64;
  int lane = rem % 64;
  const float* W = (stage == 0) ? Wd2 : (stage == 1) ? Wg1 : Wg2;
  short8 o;
#pragma unroll
  for (int j = 0; j < 8; ++j) {
    int k = ks * 32 + (lane >> 4) * 8 + j;
    int n = nt * 16 + (lane & 15);
    o[j] = f2bf(W[k * 128 + n]);
  }
  *reinterpret_cast<short8*>(wsw + (size_t)t * 8) = o;
}

// ---------------------------------------------------------------------------
// MFMA attention: 4 waves/block, one point per wave. M=16 neighbors,
// N=128 (8 tiles), K=128 (4 steps) per stage; 3 MFMA stages (Wd2,Wg1,Wg2).
// Verified 16x16x32 layouts: A: m=lane&15, k=(lane>>4)*8+j; B: n=lane&15,
// same k; C/D: col=lane&15, row=(lane>>4)*4+reg.
// ---------------------------------------------------------------------------
__global__ __launch_bounds__(256, 2) void attn_mfma_kernel(
    const float* __restrict__ xyz, const int* __restrict__ knn,
    const float* __restrict__ qv, const float* __restrict__ kv,
    const float* __restrict__ vv, const short* __restrict__ wsw,
    const float* __restrict__ Wd1, const float* __restrict__ bd1,
    const float* __restrict__ bd2, const float* __restrict__ bg1,
    const float* __restrict__ bg2, float* __restrict__ res_ws,
    float* __restrict__ out_attn) {
  const int wv = threadIdx.x >> 6;
  const int lane = threadIdx.x & 63;
  const int g = lane >> 4;   // lane group 0..3
  const int c = lane & 15;   // column-in-tile / A-row
  const int bn = blockIdx.x * 4 + wv;
  const int b = bn >> 12;

  // per-wave LDS: conv = 16 rows x 136 bf16 (stride 272B, 16B-aligned rows)
  __shared__ __attribute__((aligned(16))) short conv[4][16 * 136];
  __shared__ int sidx[4][16];
  __shared__ float sdelta[4][64];  // [16][4] padded

  if (lane < 16) sidx[wv][lane] = knn[(size_t)bn * 16 + lane];
  __syncthreads();
  if (lane < 48) {
    int k = lane / 3, cc = lane % 3;
    sdelta[wv][k * 4 + cc] = xyz[(size_t)bn * 3 + cc] -
                             xyz[((size_t)(b << 12) + sidx[wv][k]) * 3 + cc];
  }
  __syncthreads();

  // ---- P1 = relu(delta @ Wd1 + bd1) directly as A-fragments ----
  short8 af[4];
  {
    float ddx = sdelta[wv][c * 4 + 0];
    float ddy = sdelta[wv][c * 4 + 1];
    float ddz = sdelta[wv][c * 4 + 2];
#pragma unroll
    for (int s = 0; s < 4; ++s) {
#pragma unroll
      for (int j = 0; j < 8; ++j) {
        int d = s * 32 + g * 8 + j;
        float v = fmaf(ddz, Wd1[256 + d],
                       fmaf(ddy, Wd1[128 + d], fmaf(ddx, Wd1[d], bd1[d])));
        af[s][j] = f2bf(fmaxf(v, 0.f));
      }
    }
  }

  // per-nt scalars
  float qc[8], bd2v[8], bg1v[8], bg2v[8];
#pragma unroll
  for (int nt = 0; nt < 8; ++nt) {
    qc[nt] = qv[(size_t)bn * 128 + nt * 16 + c];
    bd2v[nt] = bd2[nt * 16 + c];
    bg1v[nt] = bg1[nt * 16 + c];
    bg2v[nt] = bg2[nt * 16 + c];
  }

  floatx4 acc[8];

  // ---- stage 1: PE = P1 @ Wd2 + bd2 ----
#pragma unroll
  for (int nt = 0; nt < 8; ++nt) acc[nt] = (floatx4){0.f, 0.f, 0.f, 0.f};
  {
    const short* Wst = wsw;  // stage 0
#pragma unroll
    for (int ks = 0; ks < 4; ++ks) {
#pragma unroll
      for (int nt = 0; nt < 8; ++nt) {
        short8 bf = *reinterpret_cast<const short8*>(
            Wst + ((size_t)(nt * 4 + ks) * 64 + lane) * 8);
        acc[nt] = __builtin_amdgcn_mfma_f32_16x16x32_bf16(af[ks], bf, acc[nt],
                                                          0, 0, 0);
      }
    }
  }

  // ---- H = q - kf + PE ; PE kept fp32 ; H -> LDS (bf16, C-layout) ----
  float PE[8][4];
  int idxr[4];
#pragma unroll
  for (int r = 0; r < 4; ++r) idxr[r] = sidx[wv][g * 4 + r];
#pragma unroll
  for (int nt = 0; nt < 8; ++nt) {
#pragma unroll
    for (int r = 0; r < 4; ++r) {
      float pe = acc[nt][r] + bd2v[nt];
      PE[nt][r] = pe;
      float kvv = kv[((size_t)(b << 12) + idxr[r]) * 128 + nt * 16 + c];
      conv[wv][(g * 4 + r) * 136 + nt * 16 + c] = f2bf(qc[nt] - kvv + pe);
    }
  }
  __syncthreads();
#pragma unroll
  for (int s = 0; s < 4; ++s)
    af[s] = *reinterpret_cast<const short8*>(&conv[wv][c * 136 + s * 32 + g * 8]);
  __syncthreads();

  // ---- stage 2: G = relu(H @ Wg1 + bg1) ----
#pragma unroll
  for (int nt = 0; nt < 8; ++nt) acc[nt] = (floatx4){0.f, 0.f, 0.f, 0.f};
  {
    const short* Wst = wsw + 16384;  // stage 1
#pragma unroll
    for (int ks = 0; ks < 4; ++ks) {
#pragma unroll
      for (int nt = 0; nt < 8; ++nt) {
        short8 bf = *reinterpret_cast<const short8*>(
            Wst + ((size_t)(nt * 4 + ks) * 64 + lane) * 8);
        acc[nt] = __builtin_amdgcn_mfma_f32_16x16x32_bf16(af[ks], bf, acc[nt],
                                                          0, 0, 0);
      }
    }
  }
#pragma unroll
  for (int nt = 0; nt < 8; ++nt) {
#pragma unroll
    for (int r = 0; r < 4; ++r) {
      conv[wv][(g * 4 + r) * 136 + nt * 16 + c] =
          f2bf(fmaxf(acc[nt][r] + bg1v[nt], 0.f));
    }
  }
  __syncthreads();
#pragma unroll
  for (int s = 0; s < 4; ++s)
    af[s] = *reinterpret_cast<const short8*>(&conv[wv][c * 136 + s * 32 + g * 8]);
  __syncthreads();

  // ---- stage 3: logits = G @ Wg2 + bg2 ----
#pragma unroll
  for (int nt = 0; nt < 8; ++nt) acc[nt] = (floatx4){0.f, 0.f, 0.f, 0.f};
  {
    const short* Wst = wsw + 32768;  // stage 2
#pragma unroll
    for (int ks = 0; ks < 4; ++ks) {
#pragma unroll
      for (int nt = 0; nt < 8; ++nt) {
        short8 bf = *reinterpret_cast<const short8*>(
            Wst + ((size_t)(nt * 4 + ks) * 64 + lane) * 8);
        acc[nt] = __builtin_amdgcn_mfma_f32_16x16x32_bf16(af[ks], bf, acc[nt],
                                                          0, 0, 0);
      }
    }
  }

  // ---- softmax over neighbors (rows): 4 local regs + shfl_xor(16,32) ----
  const float inv = 0.0883883476483184f;  // 1/sqrt(128)
  float resv[8];
#pragma unroll
  for (int nt = 0; nt < 8; ++nt) {
    float l0 = (acc[nt][0] + bg2v[nt]) * inv;
    float l1 = (acc[nt][1] + bg2v[nt]) * inv;
    float l2 = (acc[nt][2] + bg2v[nt]) * inv;
    float l3 = (acc[nt][3] + bg2v[nt]) * inv;
    float m4 = fmaxf(fmaxf(l0, l1), fmaxf(l2, l3));
    m4 = fmaxf(m4, __shfl_xor(m4, 16));
    m4 = fmaxf(m4, __shfl_xor(m4, 32));
    float e0 = expf(l0 - m4), e1 = expf(l1 - m4);
    float e2 = expf(l2 - m4), e3 = expf(l3 - m4);
    float s4 = e0 + e1 + e2 + e3;
    s4 += __shfl_xor(s4, 16);
    s4 += __shfl_xor(s4, 32);
    float rs = 1.f / s4;
    float a0 = e0 * rs, a1 = e1 * rs, a2 = e2 * rs, a3 = e3 * rs;
    size_t base = ((size_t)bn * 16 + g * 4) * 128 + nt * 16 + c;
    out_attn[base + 0 * 128] = a0;
    out_attn[base + 1 * 128] = a1;
    out_attn[base + 2 * 128] = a2;
    out_attn[base + 3 * 128] = a3;
    float r = 0.f;
    {
      float v0 = vv[((size_t)(b << 12) + idxr[0]) * 128 + nt * 16 + c];
      float v1 = vv[((size_t)(b << 12) + idxr[1]) * 128 + nt * 16 + c];
      float v2 = vv[((size_t)(b << 12) + idxr[2]) * 128 + nt * 16 + c];
      float v3 = vv[((size_t)(b << 12) + idxr[3]) * 128 + nt * 16 + c];
      r = fmaf(a0, v0 + PE[nt][0], r);
      r = fmaf(a1, v1 + PE[nt][1], r);
      r = fmaf(a2, v2 + PE[nt][2], r);
      r = fmaf(a3, v3 + PE[nt][3], r);
    }
    r += __shfl_xor(r, 16);
    r += __shfl_xor(r, 32);
    resv[nt] = r;
  }
  if (g == 0) {
#pragma unroll
    for (int nt = 0; nt < 8; ++nt)
      res_ws[(size_t)bn * 128 + nt * 16 + c] = resv[nt];
  }
}

// ---------------------------------------------------------------------------
// Epilogue: out_res = res @ W2 + b2 + pre   (16 points/block, mv16)
// ---------------------------------------------------------------------------
__global__ __launch_bounds__(128, 2) void epilogue_kernel(
    const float* __restrict__ res_ws, const float* __restrict__ W2,
    const float* __restrict__ b2, const float* __restrict__ pre,
    float* __restrict__ out_res) {
  const int t = threadIdx.x;
  const int g0 = blockIdx.x * 16;
  __shared__ __attribute__((aligned(16))) float buf[16 * 128];
#pragma unroll
  for (int p = 0; p < 16; ++p)
    buf[p * 128 + t] = res_ws[(size_t)(g0 + p) * 128 + t];
  __syncthreads();
  float acc[16];
  float bb = b2[t];
#pragma unroll
  for (int p = 0; p < 16; ++p)
    acc[p] = bb + pre[(size_t)(g0 + p) * 128 + t];
  mv16(W2 + t, buf, acc);
#pragma unroll
  for (int p = 0; p < 16; ++p)
    out_res[(size_t)(g0 + p) * 128 + t] = acc[p];
}

extern "C" void kernel_launch(void* const* d_in, const int* in_sizes, int n_in,
                              void* d_out, int out_size, void* d_ws,
                              size_t ws_size, hipStream_t stream) {
  const float* xyz = (const float*)d_in[0];
  const float* W0a = (const float*)d_in[1];
  const float* b0a = (const float*)d_in[2];
  const float* W0b = (const float*)d_in[3];
  const float* b0b = (const float*)d_in[4];
  const float* W1 = (const float*)d_in[5];
  const float* b1 = (const float*)d_in[6];
  const float* W2 = (const float*)d_in[7];
  const float* b2 = (const float*)d_in[8];
  const float* Wd1 = (const float*)d_in[9];
  const float* bd1 = (const float*)d_in[10];
  const float* Wd2 = (const float*)d_in[11];
  const float* bd2 = (const float*)d_in[12];
  const float* Wg1 = (const float*)d_in[13];
  const float* bg1 = (const float*)d_in[14];
  const float* Wg2 = (const float*)d_in[15];
  const float* bg2 = (const float*)d_in[16];
  const float* Wq = (const float*)d_in[17];
  const float* Wk = (const float*)d_in[18];
  const float* Wv = (const float*)d_in[19];

  char* ws = (char*)d_ws;
  int* knn = (int*)ws;                                  // 1 MB
  float* pre = (float*)(ws + (1 << 20));                // 8 MB
  float* qv = (float*)(ws + (9 << 20));                 // 8 MB
  float* kv = (float*)(ws + (17 << 20));                // 8 MB
  float* vv = (float*)(ws + (25 << 20));                // 8 MB
  float* res_ws = (float*)(ws + (33 << 20));            // 8 MB
  short* wsw = (short*)(ws + (41 << 20));               // 96 KB bf16 B-frags

  float* out_res = (float*)d_out;
  float* out_attn = out_res + (size_t)BN * DD;

  hipLaunchKernelGGL(swz_kernel, dim3(24), dim3(256), 0, stream, Wd2, Wg1, Wg2,
                     wsw);
  hipLaunchKernelGGL(knn_kernel, dim3(16384), dim3(256), 0, stream, xyz, knn);
  hipLaunchKernelGGL(point_mlp_kernel, dim3(1024), dim3(128), 0, stream, xyz,
                     W0a, b0a, W0b, b0b, W1, b1, Wq, Wk, Wv, pre, qv, kv, vv);
  hipLaunchKernelGGL(attn_mfma_kernel, dim3(4096), dim3(256), 0, stream, xyz,
                     knn, qv, kv, vv, wsw, Wd1, bd1, bd2, bg1, bg2, res_ws,
                     out_attn);
  hipLaunchKernelGGL(epilogue_kernel, dim3(1024), dim3(128), 0, stream, res_ws,
                     W2, b2, pre, out_res);
}

// Round 5
// 555.956 us; speedup vs baseline: 3.9928x; 3.9928x over previous
//
#include <hip/hip_runtime.h>
#include <math.h>

#define BB 4
#define NN 4096
#define KNNK 16
#define DD 128
#define BN (BB*NN)

typedef __attribute__((ext_vector_type(8))) short short8;   // 8 bf16
typedef __attribute__((ext_vector_type(4))) float floatx4;  // MFMA acc

__device__ __forceinline__ short f2bf(float x) {
  unsigned u = __float_as_uint(x);
  unsigned r = (u + 0x7fffu + ((u >> 16) & 1u)) >> 16;
  return (short)r;
}

// ---------------------------------------------------------------------------
// mv16: acc[p] += sum_f A[p][f] * W[f*128 + t]  (A in LDS, wave-broadcast reads)
// ---------------------------------------------------------------------------
__device__ __forceinline__ void mv16(const float* __restrict__ Wcol,
                                     const float* __restrict__ A,
                                     float acc[16]) {
#pragma unroll 2
  for (int f4 = 0; f4 < 32; ++f4) {
    float w0 = Wcol[(4 * f4 + 0) * 128];
    float w1 = Wcol[(4 * f4 + 1) * 128];
    float w2 = Wcol[(4 * f4 + 2) * 128];
    float w3 = Wcol[(4 * f4 + 3) * 128];
#pragma unroll
    for (int p = 0; p < 16; ++p) {
      float4 a = *reinterpret_cast<const float4*>(A + p * 128 + 4 * f4);
      acc[p] = fmaf(a.w, w3, fmaf(a.z, w2, fmaf(a.y, w1, fmaf(a.x, w0, acc[p]))));
    }
  }
}

// ---------------------------------------------------------------------------
// KNN v3: one WAVE per query, no LDS (round-4 lesson: u64 lists at 128B
// stride = all-bank-0 conflicts, 9.2e7 conflict cycles). Lane sorts its 64
// candidates in 4 register-sorted batches, bitonic-merges into running
// top-16, then 6 shfl_xor levels converge all lanes to the wave top-16.
// Keys: (monotone_u32(dist)<<32)|idx -> u64 ascending == top_k order.
// ---------------------------------------------------------------------------
__device__ __forceinline__ void ce64(unsigned long long& a,
                                     unsigned long long& b) {
  unsigned long long x = a, y = b;
  bool sw = y < x;
  a = sw ? y : x;
  b = sw ? x : y;
}

__device__ __forceinline__ void sort16(unsigned long long v[16]) {
#define CE(i, j) ce64(v[i], v[j]);
  CE(0, 1) CE(2, 3) CE(4, 5) CE(6, 7) CE(8, 9) CE(10, 11) CE(12, 13) CE(14, 15)
  CE(0, 2) CE(1, 3) CE(4, 6) CE(5, 7) CE(8, 10) CE(9, 11) CE(12, 14) CE(13, 15)
  CE(1, 2) CE(5, 6) CE(9, 10) CE(13, 14)
  CE(0, 4) CE(1, 5) CE(2, 6) CE(3, 7) CE(8, 12) CE(9, 13) CE(10, 14) CE(11, 15)
  CE(2, 4) CE(3, 5) CE(10, 12) CE(11, 13)
  CE(1, 2) CE(3, 4) CE(5, 6) CE(9, 10) CE(11, 12) CE(13, 14)
  CE(0, 8) CE(1, 9) CE(2, 10) CE(3, 11) CE(4, 12) CE(5, 13) CE(6, 14) CE(7, 15)
  CE(4, 8) CE(5, 9) CE(6, 10) CE(7, 11)
  CE(2, 4) CE(3, 5) CE(6, 8) CE(7, 9) CE(10, 12) CE(11, 13)
  CE(1, 2) CE(3, 4) CE(5, 6) CE(7, 8) CE(9, 10) CE(11, 12) CE(13, 14)
#undef CE
}

// sort a 16-element bitonic sequence ascending (Batcher merge: 32 CEs)
__device__ __forceinline__ void bitonic16(unsigned long long m[16]) {
#pragma unroll
  for (int s = 8; s >= 1; s >>= 1) {
#pragma unroll
    for (int i = 0; i < 16; ++i) {
      if ((i & s) == 0) ce64(m[i], m[i + s]);
    }
  }
}

__global__ __launch_bounds__(256, 4) void knn_kernel(const float* __restrict__ xyz,
                                                     int* __restrict__ knn) {
  const int wv = threadIdx.x >> 6;
  const int lane = threadIdx.x & 63;
  const int q = blockIdx.x * 4 + wv;
  const int b = q >> 12;
  const int n = q & 4095;
  const float* xb = xyz + (size_t)b * NN * 3;

  const float qx = xb[n * 3 + 0], qy = xb[n * 3 + 1], qz = xb[n * 3 + 2];
  const float qsq = __fadd_rn(__fadd_rn(__fmul_rn(qx, qx), __fmul_rn(qy, qy)),
                              __fmul_rn(qz, qz));

  unsigned long long top[16];
#pragma unroll
  for (int batch = 0; batch < 4; ++batch) {
    unsigned long long v[16];
#pragma unroll
    for (int i = 0; i < 16; ++i) {
      const int c = (batch * 16 + i) * 64 + lane;
      float cx = xb[c * 3 + 0], cy = xb[c * 3 + 1], cz = xb[c * 3 + 2];
      float csq = __fadd_rn(__fadd_rn(__fmul_rn(cx, cx), __fmul_rn(cy, cy)),
                            __fmul_rn(cz, cz));
      float dot = __fadd_rn(__fadd_rn(__fmul_rn(qx, cx), __fmul_rn(qy, cy)),
                            __fmul_rn(qz, cz));
      float d = __fadd_rn(__fsub_rn(qsq, __fmul_rn(2.0f, dot)), csq);
      unsigned u = __float_as_uint(d);
      u = (u & 0x80000000u) ? ~u : (u | 0x80000000u);  // monotone float->uint
      v[i] = ((unsigned long long)u << 32) | (unsigned)c;
    }
    sort16(v);
    if (batch == 0) {
#pragma unroll
      for (int i = 0; i < 16; ++i) top[i] = v[i];
    } else {
      unsigned long long m[16];
#pragma unroll
      for (int i = 0; i < 16; ++i) {
        unsigned long long x = top[i], y = v[15 - i];
        m[i] = (y < x) ? y : x;  // min(asc, desc) -> bitonic lower half
      }
      bitonic16(m);
#pragma unroll
      for (int i = 0; i < 16; ++i) top[i] = m[i];
    }
  }

  // cross-lane merge: after level with mask m, lanes differing in bit m hold
  // identical lists (min-with-reversed-partner is symmetric). 6 levels -> all.
#pragma unroll
  for (int mask = 1; mask <= 32; mask <<= 1) {
    unsigned long long oth[16];
#pragma unroll
    for (int i = 0; i < 16; ++i) {
      unsigned long long x = top[15 - i];
      unsigned lo = __shfl_xor((unsigned)(x & 0xffffffffu), mask);
      unsigned hi = __shfl_xor((unsigned)(x >> 32), mask);
      unsigned long long y = ((unsigned long long)hi << 32) | lo;
      oth[i] = (y < top[i]) ? y : top[i];
    }
    bitonic16(oth);
#pragma unroll
    for (int i = 0; i < 16; ++i) top[i] = oth[i];
  }

  if (lane == 0) {
    int* outp = knn + (size_t)q * KNNK;
#pragma unroll
    for (int k = 0; k < 16; ++k)
      outp[k] = (int)(unsigned)(top[k] & 0xffffffffu);
  }
}

// ---------------------------------------------------------------------------
// Per-point MLP chain (unchanged from verified baseline)
// ---------------------------------------------------------------------------
__global__ __launch_bounds__(128, 2) void point_mlp_kernel(
    const float* __restrict__ xyz, const float* __restrict__ W0a,
    const float* __restrict__ b0a, const float* __restrict__ W0b,
    const float* __restrict__ b0b, const float* __restrict__ W1,
    const float* __restrict__ b1, const float* __restrict__ Wq,
    const float* __restrict__ Wk, const float* __restrict__ Wv,
    float* __restrict__ pre, float* __restrict__ qv, float* __restrict__ kv,
    float* __restrict__ vv) {
  const int t = threadIdx.x;
  const int g0 = blockIdx.x * 16;
  __shared__ float4 pool[2 * 512 + 16];
  float* bufA = (float*)pool;
  float* bufB = bufA + 2048;
  float* xs = bufB + 2048;  // [16][4]
  if (t < 48) {
    int p = t / 3, c = t % 3;
    xs[p * 4 + c] = xyz[(size_t)(g0 + p) * 3 + c];
  }
  __syncthreads();
  {
    float wa0 = W0a[t], wa1 = W0a[128 + t], wa2 = W0a[256 + t], ba = b0a[t];
#pragma unroll
    for (int p = 0; p < 16; ++p) {
      float v = fmaf(xs[p * 4 + 2], wa2,
                     fmaf(xs[p * 4 + 1], wa1, fmaf(xs[p * 4 + 0], wa0, ba)));
      bufA[p * 128 + t] = fmaxf(v, 0.f);
    }
  }
  __syncthreads();
  float acc[16];
  {
    float bb = b0b[t];
#pragma unroll
    for (int p = 0; p < 16; ++p) acc[p] = bb;
    mv16(W0b + t, bufA, acc);
#pragma unroll
    for (int p = 0; p < 16; ++p) {
      bufB[p * 128 + t] = acc[p];
      pre[(size_t)(g0 + p) * 128 + t] = acc[p];
    }
  }
  __syncthreads();
  {
    float bb = b1[t];
#pragma unroll
    for (int p = 0; p < 16; ++p) acc[p] = bb;
    mv16(W1 + t, bufB, acc);
#pragma unroll
    for (int p = 0; p < 16; ++p) bufA[p * 128 + t] = acc[p];
  }
  __syncthreads();
  {
#pragma unroll
    for (int p = 0; p < 16; ++p) acc[p] = 0.f;
    mv16(Wq + t, bufA, acc);
#pragma unroll
    for (int p = 0; p < 16; ++p) qv[(size_t)(g0 + p) * 128 + t] = acc[p];
  }
  {
#pragma unroll
    for (int p = 0; p < 16; ++p) acc[p] = 0.f;
    mv16(Wk + t, bufA, acc);
#pragma unroll
    for (int p = 0; p < 16; ++p) kv[(size_t)(g0 + p) * 128 + t] = acc[p];
  }
  {
#pragma unroll
    for (int p = 0; p < 16; ++p) acc[p] = 0.f;
    mv16(Wv + t, bufA, acc);
#pragma unroll
    for (int p = 0; p < 16; ++p) vv[(size_t)(g0 + p) * 128 + t] = acc[p];
  }
}

// ---------------------------------------------------------------------------
// Weight pre-swizzle: Wd2/Wg1/Wg2 (fp32 [k(128)][n(128)]) -> bf16 B-fragment
// order for mfma_f32_16x16x32_bf16: wsw[stage][nt][ks][lane][j],
// element = W[(ks*32 + (lane>>4)*8 + j)*128 + nt*16 + (lane&15)].
// ---------------------------------------------------------------------------
__global__ void swz_kernel(const float* __restrict__ Wd2,
                           const float* __restrict__ Wg1,
                           const float* __restrict__ Wg2,
                           short* __restrict__ wsw) {
  int t = blockIdx.x * 256 + threadIdx.x;  // [0, 6144): [stage][nt][ks][lane]
  if (t >= 3 * 2048) return;
  int stage = t / 2048;
  int rem = t % 2048;
  int nt = rem / 256;
  int ks = (rem % 256) / 64;
  int lane = rem % 64;
  const float* W = (stage == 0) ? Wd2 : (stage == 1) ? Wg1 : Wg2;
  short8 o;
#pragma unroll
  for (int j = 0; j < 8; ++j) {
    int k = ks * 32 + (lane >> 4) * 8 + j;
    int n = nt * 16 + (lane & 15);
    o[j] = f2bf(W[k * 128 + n]);
  }
  *reinterpret_cast<short8*>(wsw + (size_t)t * 8) = o;
}

// ---------------------------------------------------------------------------
// MFMA attention: 4 waves/block, one point per wave. M=16 neighbors,
// N=128 (8 tiles), K=128 (4 steps) per stage; 3 MFMA stages (Wd2,Wg1,Wg2).
// Verified 16x16x32 layouts: A: m=lane&15, k=(lane>>4)*8+j; B: n=lane&15,
// same k; C/D: col=lane&15, row=(lane>>4)*4+reg.
// ---------------------------------------------------------------------------
__global__ __launch_bounds__(256, 2) void attn_mfma_kernel(
    const float* __restrict__ xyz, const int* __restrict__ knn,
    const float* __restrict__ qv, const float* __restrict__ kv,
    const float* __restrict__ vv, const short* __restrict__ wsw,
    const float* __restrict__ Wd1, const float* __restrict__ bd1,
    const float* __restrict__ bd2, const float* __restrict__ bg1,
    const float* __restrict__ bg2, float* __restrict__ res_ws,
    float* __restrict__ out_attn) {
  const int wv = threadIdx.x >> 6;
  const int lane = threadIdx.x & 63;
  const int g = lane >> 4;   // lane group 0..3
  const int c = lane & 15;   // column-in-tile / A-row
  const int bn = blockIdx.x * 4 + wv;
  const int b = bn >> 12;

  // per-wave LDS: conv = 16 rows x 136 bf16 (stride 272B, 16B-aligned rows)
  __shared__ __attribute__((aligned(16))) short conv[4][16 * 136];
  __shared__ int sidx[4][16];
  __shared__ float sdelta[4][64];  // [16][4] padded

  if (lane < 16) sidx[wv][lane] = knn[(size_t)bn * 16 + lane];
  __syncthreads();
  if (lane < 48) {
    int k = lane / 3, cc = lane % 3;
    sdelta[wv][k * 4 + cc] = xyz[(size_t)bn * 3 + cc] -
                             xyz[((size_t)(b << 12) + sidx[wv][k]) * 3 + cc];
  }
  __syncthreads();

  // ---- P1 = relu(delta @ Wd1 + bd1) directly as A-fragments ----
  short8 af[4];
  {
    float ddx = sdelta[wv][c * 4 + 0];
    float ddy = sdelta[wv][c * 4 + 1];
    float ddz = sdelta[wv][c * 4 + 2];
#pragma unroll
    for (int s = 0; s < 4; ++s) {
#pragma unroll
      for (int j = 0; j < 8; ++j) {
        int d = s * 32 + g * 8 + j;
        float v = fmaf(ddz, Wd1[256 + d],
                       fmaf(ddy, Wd1[128 + d], fmaf(ddx, Wd1[d], bd1[d])));
        af[s][j] = f2bf(fmaxf(v, 0.f));
      }
    }
  }

  // per-nt scalars
  float qc[8], bd2v[8], bg1v[8], bg2v[8];
#pragma unroll
  for (int nt = 0; nt < 8; ++nt) {
    qc[nt] = qv[(size_t)bn * 128 + nt * 16 + c];
    bd2v[nt] = bd2[nt * 16 + c];
    bg1v[nt] = bg1[nt * 16 + c];
    bg2v[nt] = bg2[nt * 16 + c];
  }

  floatx4 acc[8];

  // ---- stage 1: PE = P1 @ Wd2 + bd2 ----
#pragma unroll
  for (int nt = 0; nt < 8; ++nt) acc[nt] = (floatx4){0.f, 0.f, 0.f, 0.f};
  {
    const short* Wst = wsw;  // stage 0
#pragma unroll
    for (int ks = 0; ks < 4; ++ks) {
#pragma unroll
      for (int nt = 0; nt < 8; ++nt) {
        short8 bf = *reinterpret_cast<const short8*>(
            Wst + ((size_t)(nt * 4 + ks) * 64 + lane) * 8);
        acc[nt] = __builtin_amdgcn_mfma_f32_16x16x32_bf16(af[ks], bf, acc[nt],
                                                          0, 0, 0);
      }
    }
  }

  // ---- H = q - kf + PE ; PE kept fp32 ; H -> LDS (bf16, C-layout) ----
  float PE[8][4];
  int idxr[4];
#pragma unroll
  for (int r = 0; r < 4; ++r) idxr[r] = sidx[wv][g * 4 + r];
#pragma unroll
  for (int nt = 0; nt < 8; ++nt) {
#pragma unroll
    for (int r = 0; r < 4; ++r) {
      float pe = acc[nt][r] + bd2v[nt];
      PE[nt][r] = pe;
      float kvv = kv[((size_t)(b << 12) + idxr[r]) * 128 + nt * 16 + c];
      conv[wv][(g * 4 + r) * 136 + nt * 16 + c] = f2bf(qc[nt] - kvv + pe);
    }
  }
  __syncthreads();
#pragma unroll
  for (int s = 0; s < 4; ++s)
    af[s] = *reinterpret_cast<const short8*>(&conv[wv][c * 136 + s * 32 + g * 8]);
  __syncthreads();

  // ---- stage 2: G = relu(H @ Wg1 + bg1) ----
#pragma unroll
  for (int nt = 0; nt < 8; ++nt) acc[nt] = (floatx4){0.f, 0.f, 0.f, 0.f};
  {
    const short* Wst = wsw + 16384;  // stage 1
#pragma unroll
    for (int ks = 0; ks < 4; ++ks) {
#pragma unroll
      for (int nt = 0; nt < 8; ++nt) {
        short8 bf = *reinterpret_cast<const short8*>(
            Wst + ((size_t)(nt * 4 + ks) * 64 + lane) * 8);
        acc[nt] = __builtin_amdgcn_mfma_f32_16x16x32_bf16(af[ks], bf, acc[nt],
                                                          0, 0, 0);
      }
    }
  }
#pragma unroll
  for (int nt = 0; nt < 8; ++nt) {
#pragma unroll
    for (int r = 0; r < 4; ++r) {
      conv[wv][(g * 4 + r) * 136 + nt * 16 + c] =
          f2bf(fmaxf(acc[nt][r] + bg1v[nt], 0.f));
    }
  }
  __syncthreads();
#pragma unroll
  for (int s = 0; s < 4; ++s)
    af[s] = *reinterpret_cast<const short8*>(&conv[wv][c * 136 + s * 32 + g * 8]);
  __syncthreads();

  // ---- stage 3: logits = G @ Wg2 + bg2 ----
#pragma unroll
  for (int nt = 0; nt < 8; ++nt) acc[nt] = (floatx4){0.f, 0.f, 0.f, 0.f};
  {
    const short* Wst = wsw + 32768;  // stage 2
#pragma unroll
    for (int ks = 0; ks < 4; ++ks) {
#pragma unroll
      for (int nt = 0; nt < 8; ++nt) {
        short8 bf = *reinterpret_cast<const short8*>(
            Wst + ((size_t)(nt * 4 + ks) * 64 + lane) * 8);
        acc[nt] = __builtin_amdgcn_mfma_f32_16x16x32_bf16(af[ks], bf, acc[nt],
                                                          0, 0, 0);
      }
    }
  }

  // ---- softmax over neighbors (rows): 4 local regs + shfl_xor(16,32) ----
  const float inv = 0.0883883476483184f;  // 1/sqrt(128)
  float resv[8];
#pragma unroll
  for (int nt = 0; nt < 8; ++nt) {
    float l0 = (acc[nt][0] + bg2v[nt]) * inv;
    float l1 = (acc[nt][1] + bg2v[nt]) * inv;
    float l2 = (acc[nt][2] + bg2v[nt]) * inv;
    float l3 = (acc[nt][3] + bg2v[nt]) * inv;
    float m4 = fmaxf(fmaxf(l0, l1), fmaxf(l2, l3));
    m4 = fmaxf(m4, __shfl_xor(m4, 16));
    m4 = fmaxf(m4, __shfl_xor(m4, 32));
    float e0 = expf(l0 - m4), e1 = expf(l1 - m4);
    float e2 = expf(l2 - m4), e3 = expf(l3 - m4);
    float s4 = e0 + e1 + e2 + e3;
    s4 += __shfl_xor(s4, 16);
    s4 += __shfl_xor(s4, 32);
    float rs = 1.f / s4;
    float a0 = e0 * rs, a1 = e1 * rs, a2 = e2 * rs, a3 = e3 * rs;
    size_t base = ((size_t)bn * 16 + g * 4) * 128 + nt * 16 + c;
    out_attn[base + 0 * 128] = a0;
    out_attn[base + 1 * 128] = a1;
    out_attn[base + 2 * 128] = a2;
    out_attn[base + 3 * 128] = a3;
    float r = 0.f;
    {
      float v0 = vv[((size_t)(b << 12) + idxr[0]) * 128 + nt * 16 + c];
      float v1 = vv[((size_t)(b << 12) + idxr[1]) * 128 + nt * 16 + c];
      float v2 = vv[((size_t)(b << 12) + idxr[2]) * 128 + nt * 16 + c];
      float v3 = vv[((size_t)(b << 12) + idxr[3]) * 128 + nt * 16 + c];
      r = fmaf(a0, v0 + PE[nt][0], r);
      r = fmaf(a1, v1 + PE[nt][1], r);
      r = fmaf(a2, v2 + PE[nt][2], r);
      r = fmaf(a3, v3 + PE[nt][3], r);
    }
    r += __shfl_xor(r, 16);
    r += __shfl_xor(r, 32);
    resv[nt] = r;
  }
  if (g == 0) {
#pragma unroll
    for (int nt = 0; nt < 8; ++nt)
      res_ws[(size_t)bn * 128 + nt * 16 + c] = resv[nt];
  }
}

// ---------------------------------------------------------------------------
// Epilogue: out_res = res @ W2 + b2 + pre   (16 points/block, mv16)
// ---------------------------------------------------------------------------
__global__ __launch_bounds__(128, 2) void epilogue_kernel(
    const float* __restrict__ res_ws, const float* __restrict__ W2,
    const float* __restrict__ b2, const float* __restrict__ pre,
    float* __restrict__ out_res) {
  const int t = threadIdx.x;
  const int g0 = blockIdx.x * 16;
  __shared__ __attribute__((aligned(16))) float buf[16 * 128];
#pragma unroll
  for (int p = 0; p < 16; ++p)
    buf[p * 128 + t] = res_ws[(size_t)(g0 + p) * 128 + t];
  __syncthreads();
  float acc[16];
  float bb = b2[t];
#pragma unroll
  for (int p = 0; p < 16; ++p)
    acc[p] = bb + pre[(size_t)(g0 + p) * 128 + t];
  mv16(W2 + t, buf, acc);
#pragma unroll
  for (int p = 0; p < 16; ++p)
    out_res[(size_t)(g0 + p) * 128 + t] = acc[p];
}

extern "C" void kernel_launch(void* const* d_in, const int* in_sizes, int n_in,
                              void* d_out, int out_size, void* d_ws,
                              size_t ws_size, hipStream_t stream) {
  const float* xyz = (const float*)d_in[0];
  const float* W0a = (const float*)d_in[1];
  const float* b0a = (const float*)d_in[2];
  const float* W0b = (const float*)d_in[3];
  const float* b0b = (const float*)d_in[4];
  const float* W1 = (const float*)d_in[5];
  const float* b1 = (const float*)d_in[6];
  const float* W2 = (const float*)d_in[7];
  const float* b2 = (const float*)d_in[8];
  const float* Wd1 = (const float*)d_in[9];
  const float* bd1 = (const float*)d_in[10];
  const float* Wd2 = (const float*)d_in[11];
  const float* bd2 = (const float*)d_in[12];
  const float* Wg1 = (const float*)d_in[13];
  const float* bg1 = (const float*)d_in[14];
  const float* Wg2 = (const float*)d_in[15];
  const float* bg2 = (const float*)d_in[16];
  const float* Wq = (const float*)d_in[17];
  const float* Wk = (const float*)d_in[18];
  const float* Wv = (const float*)d_in[19];

  char* ws = (char*)d_ws;
  int* knn = (int*)ws;                                  // 1 MB
  float* pre = (float*)(ws + (1 << 20));                // 8 MB
  float* qv = (float*)(ws + (9 << 20));                 // 8 MB
  float* kv = (float*)(ws + (17 << 20));                // 8 MB
  float* vv = (float*)(ws + (25 << 20));                // 8 MB
  float* res_ws = (float*)(ws + (33 << 20));            // 8 MB
  short* wsw = (short*)(ws + (41 << 20));               // 96 KB bf16 B-frags

  float* out_res = (float*)d_out;
  float* out_attn = out_res + (size_t)BN * DD;

  hipLaunchKernelGGL(swz_kernel, dim3(24), dim3(256), 0, stream, Wd2, Wg1, Wg2,
                     wsw);
  hipLaunchKernelGGL(knn_kernel, dim3(4096), dim3(256), 0, stream, xyz, knn);
  hipLaunchKernelGGL(point_mlp_kernel, dim3(1024), dim3(128), 0, stream, xyz,
                     W0a, b0a, W0b, b0b, W1, b1, Wq, Wk, Wv, pre, qv, kv, vv);
  hipLaunchKernelGGL(attn_mfma_kernel, dim3(4096), dim3(256), 0, stream, xyz,
                     knn, qv, kv, vv, wsw, Wd1, bd1, bd2, bg1, bg2, res_ws,
                     out_attn);
  hipLaunchKernelGGL(epilogue_kernel, dim3(1024), dim3(128), 0, stream, res_ws,
                     W2, b2, pre, out_res);
}

// Round 6
// 507.483 us; speedup vs baseline: 4.3742x; 1.0955x over previous
//
#include <hip/hip_runtime.h>
#include <math.h>

#define BB 4
#define NN 4096
#define KNNK 16
#define DD 128
#define BN (BB*NN)

typedef __attribute__((ext_vector_type(8))) short short8;   // 8 bf16
typedef __attribute__((ext_vector_type(4))) float floatx4;  // MFMA acc

__device__ __forceinline__ short f2bf(float x) {
  unsigned u = __float_as_uint(x);
  unsigned r = (u + 0x7fffu + ((u >> 16) & 1u)) >> 16;
  return (short)r;
}

// ---------------------------------------------------------------------------
// mv16: acc[p] += sum_f A[p][f] * W[f*128 + t]  (A in LDS, wave-broadcast reads)
// ---------------------------------------------------------------------------
__device__ __forceinline__ void mv16(const float* __restrict__ Wcol,
                                     const float* __restrict__ A,
                                     float acc[16]) {
#pragma unroll 2
  for (int f4 = 0; f4 < 32; ++f4) {
    float w0 = Wcol[(4 * f4 + 0) * 128];
    float w1 = Wcol[(4 * f4 + 1) * 128];
    float w2 = Wcol[(4 * f4 + 2) * 128];
    float w3 = Wcol[(4 * f4 + 3) * 128];
#pragma unroll
    for (int p = 0; p < 16; ++p) {
      float4 a = *reinterpret_cast<const float4*>(A + p * 128 + 4 * f4);
      acc[p] = fmaf(a.w, w3, fmaf(a.z, w2, fmaf(a.y, w1, fmaf(a.x, w0, acc[p]))));
    }
  }
}

// ---------------------------------------------------------------------------
// KNN v4: one WAVE per query, register-only (round-5 verified structure).
// Round-6 change: keys are order-preserving positive f64 so a compare-
// exchange is v_min_f64 + v_max_f64 (2 instrs) instead of v_cmp_lt_u64 +
// 4x v_cndmask (5). Key = 0x3FF0..0 | (monotone32(d)<<12 | idx): 44 payload
// bits in the mantissa, all keys normal f64 in [1,2), no NaN/denormal ->
// IEEE ordering == u64 ordering == top_k (dist, idx) tie-break.
// ---------------------------------------------------------------------------
__device__ __forceinline__ void ced(double& a, double& b) {
  double mn = fmin(a, b);
  double mx = fmax(a, b);
  a = mn;
  b = mx;
}

__device__ __forceinline__ void dsort16(double v[16]) {
#define CE(i, j) ced(v[i], v[j]);
  CE(0, 1) CE(2, 3) CE(4, 5) CE(6, 7) CE(8, 9) CE(10, 11) CE(12, 13) CE(14, 15)
  CE(0, 2) CE(1, 3) CE(4, 6) CE(5, 7) CE(8, 10) CE(9, 11) CE(12, 14) CE(13, 15)
  CE(1, 2) CE(5, 6) CE(9, 10) CE(13, 14)
  CE(0, 4) CE(1, 5) CE(2, 6) CE(3, 7) CE(8, 12) CE(9, 13) CE(10, 14) CE(11, 15)
  CE(2, 4) CE(3, 5) CE(10, 12) CE(11, 13)
  CE(1, 2) CE(3, 4) CE(5, 6) CE(9, 10) CE(11, 12) CE(13, 14)
  CE(0, 8) CE(1, 9) CE(2, 10) CE(3, 11) CE(4, 12) CE(5, 13) CE(6, 14) CE(7, 15)
  CE(4, 8) CE(5, 9) CE(6, 10) CE(7, 11)
  CE(2, 4) CE(3, 5) CE(6, 8) CE(7, 9) CE(10, 12) CE(11, 13)
  CE(1, 2) CE(3, 4) CE(5, 6) CE(7, 8) CE(9, 10) CE(11, 12) CE(13, 14)
#undef CE
}

// sort a 16-element bitonic sequence ascending
__device__ __forceinline__ void dbitonic16(double m[16]) {
#pragma unroll
  for (int s = 8; s >= 1; s >>= 1) {
#pragma unroll
    for (int i = 0; i < 16; ++i) {
      if ((i & s) == 0) ced(m[i], m[i + s]);
    }
  }
}

__global__ __launch_bounds__(256, 4) void knn_kernel(const float* __restrict__ xyz,
                                                     int* __restrict__ knn) {
  const int wv = threadIdx.x >> 6;
  const int lane = threadIdx.x & 63;
  const int q = blockIdx.x * 4 + wv;
  const int b = q >> 12;
  const int n = q & 4095;
  const float* xb = xyz + (size_t)b * NN * 3;

  const float qx = xb[n * 3 + 0], qy = xb[n * 3 + 1], qz = xb[n * 3 + 2];
  const float qsq = __fadd_rn(__fadd_rn(__fmul_rn(qx, qx), __fmul_rn(qy, qy)),
                              __fmul_rn(qz, qz));

  double top[16];
#pragma unroll
  for (int batch = 0; batch < 4; ++batch) {
    double v[16];
#pragma unroll
    for (int i = 0; i < 16; ++i) {
      const int c = (batch * 16 + i) * 64 + lane;
      float cx = xb[c * 3 + 0], cy = xb[c * 3 + 1], cz = xb[c * 3 + 2];
      float csq = __fadd_rn(__fadd_rn(__fmul_rn(cx, cx), __fmul_rn(cy, cy)),
                            __fmul_rn(cz, cz));
      float dot = __fadd_rn(__fadd_rn(__fmul_rn(qx, cx), __fmul_rn(qy, cy)),
                            __fmul_rn(qz, cz));
      float d = __fadd_rn(__fsub_rn(qsq, __fmul_rn(2.0f, dot)), csq);
      unsigned u = __float_as_uint(d);
      u = (u & 0x80000000u) ? ~u : (u | 0x80000000u);  // monotone float->uint
      unsigned long long key =
          0x3FF0000000000000ULL | (((unsigned long long)u << 12) | (unsigned)c);
      v[i] = __longlong_as_double((long long)key);
    }
    dsort16(v);
    if (batch == 0) {
#pragma unroll
      for (int i = 0; i < 16; ++i) top[i] = v[i];
    } else {
      double m[16];
#pragma unroll
      for (int i = 0; i < 16; ++i)
        m[i] = fmin(top[i], v[15 - i]);  // min(asc, desc) -> bitonic lower half
      dbitonic16(m);
#pragma unroll
      for (int i = 0; i < 16; ++i) top[i] = m[i];
    }
  }

  // cross-lane merge: min-with-reversed-partner is symmetric, so after the
  // level with mask m, lanes differing in bit m hold identical lists.
#pragma unroll
  for (int mask = 1; mask <= 32; mask <<= 1) {
    double oth[16];
#pragma unroll
    for (int i = 0; i < 16; ++i) {
      double y = __shfl_xor(top[15 - i], mask);
      oth[i] = fmin(y, top[i]);
    }
    dbitonic16(oth);
#pragma unroll
    for (int i = 0; i < 16; ++i) top[i] = oth[i];
  }

  if (lane == 0) {
    int* outp = knn + (size_t)q * KNNK;
#pragma unroll
    for (int k = 0; k < 16; ++k)
      outp[k] = (int)(__double_as_longlong(top[k]) & 0xFFFLL);
  }
}

// ---------------------------------------------------------------------------
// Per-point MLP chain (unchanged from verified baseline)
// ---------------------------------------------------------------------------
__global__ __launch_bounds__(128, 2) void point_mlp_kernel(
    const float* __restrict__ xyz, const float* __restrict__ W0a,
    const float* __restrict__ b0a, const float* __restrict__ W0b,
    const float* __restrict__ b0b, const float* __restrict__ W1,
    const float* __restrict__ b1, const float* __restrict__ Wq,
    const float* __restrict__ Wk, const float* __restrict__ Wv,
    float* __restrict__ pre, float* __restrict__ qv, float* __restrict__ kv,
    float* __restrict__ vv) {
  const int t = threadIdx.x;
  const int g0 = blockIdx.x * 16;
  __shared__ float4 pool[2 * 512 + 16];
  float* bufA = (float*)pool;
  float* bufB = bufA + 2048;
  float* xs = bufB + 2048;  // [16][4]
  if (t < 48) {
    int p = t / 3, c = t % 3;
    xs[p * 4 + c] = xyz[(size_t)(g0 + p) * 3 + c];
  }
  __syncthreads();
  {
    float wa0 = W0a[t], wa1 = W0a[128 + t], wa2 = W0a[256 + t], ba = b0a[t];
#pragma unroll
    for (int p = 0; p < 16; ++p) {
      float v = fmaf(xs[p * 4 + 2], wa2,
                     fmaf(xs[p * 4 + 1], wa1, fmaf(xs[p * 4 + 0], wa0, ba)));
      bufA[p * 128 + t] = fmaxf(v, 0.f);
    }
  }
  __syncthreads();
  float acc[16];
  {
    float bb = b0b[t];
#pragma unroll
    for (int p = 0; p < 16; ++p) acc[p] = bb;
    mv16(W0b + t, bufA, acc);
#pragma unroll
    for (int p = 0; p < 16; ++p) {
      bufB[p * 128 + t] = acc[p];
      pre[(size_t)(g0 + p) * 128 + t] = acc[p];
    }
  }
  __syncthreads();
  {
    float bb = b1[t];
#pragma unroll
    for (int p = 0; p < 16; ++p) acc[p] = bb;
    mv16(W1 + t, bufB, acc);
#pragma unroll
    for (int p = 0; p < 16; ++p) bufA[p * 128 + t] = acc[p];
  }
  __syncthreads();
  {
#pragma unroll
    for (int p = 0; p < 16; ++p) acc[p] = 0.f;
    mv16(Wq + t, bufA, acc);
#pragma unroll
    for (int p = 0; p < 16; ++p) qv[(size_t)(g0 + p) * 128 + t] = acc[p];
  }
  {
#pragma unroll
    for (int p = 0; p < 16; ++p) acc[p] = 0.f;
    mv16(Wk + t, bufA, acc);
#pragma unroll
    for (int p = 0; p < 16; ++p) kv[(size_t)(g0 + p) * 128 + t] = acc[p];
  }
  {
#pragma unroll
    for (int p = 0; p < 16; ++p) acc[p] = 0.f;
    mv16(Wv + t, bufA, acc);
#pragma unroll
    for (int p = 0; p < 16; ++p) vv[(size_t)(g0 + p) * 128 + t] = acc[p];
  }
}

// ---------------------------------------------------------------------------
// Weight pre-swizzle: Wd2/Wg1/Wg2 (fp32 [k(128)][n(128)]) -> bf16 B-fragment
// order for mfma_f32_16x16x32_bf16: wsw[stage][nt][ks][lane][j],
// element = W[(ks*32 + (lane>>4)*8 + j)*128 + nt*16 + (lane&15)].
// ---------------------------------------------------------------------------
__global__ void swz_kernel(const float* __restrict__ Wd2,
                           const float* __restrict__ Wg1,
                           const float* __restrict__ Wg2,
                           short* __restrict__ wsw) {
  int t = blockIdx.x * 256 + threadIdx.x;  // [0, 6144): [stage][nt][ks][lane]
  if (t >= 3 * 2048) return;
  int stage = t / 2048;
  int rem = t % 2048;
  int nt = rem / 256;
  int ks = (rem % 256) / 64;
  int lane = rem % 64;
  const float* W = (stage == 0) ? Wd2 : (stage == 1) ? Wg1 : Wg2;
  short8 o;
#pragma unroll
  for (int j = 0; j < 8; ++j) {
    int k = ks * 32 + (lane >> 4) * 8 + j;
    int n = nt * 16 + (lane & 15);
    o[j] = f2bf(W[k * 128 + n]);
  }
  *reinterpret_cast<short8*>(wsw + (size_t)t * 8) = o;
}

// ---------------------------------------------------------------------------
// MFMA attention: 4 waves/block, one point per wave. M=16 neighbors,
// N=128 (8 tiles), K=128 (4 steps) per stage; 3 MFMA stages (Wd2,Wg1,Wg2).
// Verified 16x16x32 layouts: A: m=lane&15, k=(lane>>4)*8+j; B: n=lane&15,
// same k; C/D: col=lane&15, row=(lane>>4)*4+reg.
// ---------------------------------------------------------------------------
__global__ __launch_bounds__(256, 2) void attn_mfma_kernel(
    const float* __restrict__ xyz, const int* __restrict__ knn,
    const float* __restrict__ qv, const float* __restrict__ kv,
    const float* __restrict__ vv, const short* __restrict__ wsw,
    const float* __restrict__ Wd1, const float* __restrict__ bd1,
    const float* __restrict__ bd2, const float* __restrict__ bg1,
    const float* __restrict__ bg2, float* __restrict__ res_ws,
    float* __restrict__ out_attn) {
  const int wv = threadIdx.x >> 6;
  const int lane = threadIdx.x & 63;
  const int g = lane >> 4;   // lane group 0..3
  const int c = lane & 15;   // column-in-tile / A-row
  const int bn = blockIdx.x * 4 + wv;
  const int b = bn >> 12;

  // per-wave LDS: conv = 16 rows x 136 bf16 (stride 272B, 16B-aligned rows)
  __shared__ __attribute__((aligned(16))) short conv[4][16 * 136];
  __shared__ int sidx[4][16];
  __shared__ float sdelta[4][64];  // [16][4] padded

  if (lane < 16) sidx[wv][lane] = knn[(size_t)bn * 16 + lane];
  __syncthreads();
  if (lane < 48) {
    int k = lane / 3, cc = lane % 3;
    sdelta[wv][k * 4 + cc] = xyz[(size_t)bn * 3 + cc] -
                             xyz[((size_t)(b << 12) + sidx[wv][k]) * 3 + cc];
  }
  __syncthreads();

  // ---- P1 = relu(delta @ Wd1 + bd1) directly as A-fragments ----
  short8 af[4];
  {
    float ddx = sdelta[wv][c * 4 + 0];
    float ddy = sdelta[wv][c * 4 + 1];
    float ddz = sdelta[wv][c * 4 + 2];
#pragma unroll
    for (int s = 0; s < 4; ++s) {
#pragma unroll
      for (int j = 0; j < 8; ++j) {
        int d = s * 32 + g * 8 + j;
        float v = fmaf(ddz, Wd1[256 + d],
                       fmaf(ddy, Wd1[128 + d], fmaf(ddx, Wd1[d], bd1[d])));
        af[s][j] = f2bf(fmaxf(v, 0.f));
      }
    }
  }

  // per-nt scalars
  float qc[8], bd2v[8], bg1v[8], bg2v[8];
#pragma unroll
  for (int nt = 0; nt < 8; ++nt) {
    qc[nt] = qv[(size_t)bn * 128 + nt * 16 + c];
    bd2v[nt] = bd2[nt * 16 + c];
    bg1v[nt] = bg1[nt * 16 + c];
    bg2v[nt] = bg2[nt * 16 + c];
  }

  floatx4 acc[8];

  // ---- stage 1: PE = P1 @ Wd2 + bd2 ----
#pragma unroll
  for (int nt = 0; nt < 8; ++nt) acc[nt] = (floatx4){0.f, 0.f, 0.f, 0.f};
  {
    const short* Wst = wsw;  // stage 0
#pragma unroll
    for (int ks = 0; ks < 4; ++ks) {
#pragma unroll
      for (int nt = 0; nt < 8; ++nt) {
        short8 bf = *reinterpret_cast<const short8*>(
            Wst + ((size_t)(nt * 4 + ks) * 64 + lane) * 8);
        acc[nt] = __builtin_amdgcn_mfma_f32_16x16x32_bf16(af[ks], bf, acc[nt],
                                                          0, 0, 0);
      }
    }
  }

  // ---- H = q - kf + PE ; PE kept fp32 ; H -> LDS (bf16, C-layout) ----
  float PE[8][4];
  int idxr[4];
#pragma unroll
  for (int r = 0; r < 4; ++r) idxr[r] = sidx[wv][g * 4 + r];
#pragma unroll
  for (int nt = 0; nt < 8; ++nt) {
#pragma unroll
    for (int r = 0; r < 4; ++r) {
      float pe = acc[nt][r] + bd2v[nt];
      PE[nt][r] = pe;
      float kvv = kv[((size_t)(b << 12) + idxr[r]) * 128 + nt * 16 + c];
      conv[wv][(g * 4 + r) * 136 + nt * 16 + c] = f2bf(qc[nt] - kvv + pe);
    }
  }
  __syncthreads();
#pragma unroll
  for (int s = 0; s < 4; ++s)
    af[s] = *reinterpret_cast<const short8*>(&conv[wv][c * 136 + s * 32 + g * 8]);
  __syncthreads();

  // ---- stage 2: G = relu(H @ Wg1 + bg1) ----
#pragma unroll
  for (int nt = 0; nt < 8; ++nt) acc[nt] = (floatx4){0.f, 0.f, 0.f, 0.f};
  {
    const short* Wst = wsw + 16384;  // stage 1
#pragma unroll
    for (int ks = 0; ks < 4; ++ks) {
#pragma unroll
      for (int nt = 0; nt < 8; ++nt) {
        short8 bf = *reinterpret_cast<const short8*>(
            Wst + ((size_t)(nt * 4 + ks) * 64 + lane) * 8);
        acc[nt] = __builtin_amdgcn_mfma_f32_16x16x32_bf16(af[ks], bf, acc[nt],
                                                          0, 0, 0);
      }
    }
  }
#pragma unroll
  for (int nt = 0; nt < 8; ++nt) {
#pragma unroll
    for (int r = 0; r < 4; ++r) {
      conv[wv][(g * 4 + r) * 136 + nt * 16 + c] =
          f2bf(fmaxf(acc[nt][r] + bg1v[nt], 0.f));
    }
  }
  __syncthreads();
#pragma unroll
  for (int s = 0; s < 4; ++s)
    af[s] = *reinterpret_cast<const short8*>(&conv[wv][c * 136 + s * 32 + g * 8]);
  __syncthreads();

  // ---- stage 3: logits = G @ Wg2 + bg2 ----
#pragma unroll
  for (int nt = 0; nt < 8; ++nt) acc[nt] = (floatx4){0.f, 0.f, 0.f, 0.f};
  {
    const short* Wst = wsw + 32768;  // stage 2
#pragma unroll
    for (int ks = 0; ks < 4; ++ks) {
#pragma unroll
      for (int nt = 0; nt < 8; ++nt) {
        short8 bf = *reinterpret_cast<const short8*>(
            Wst + ((size_t)(nt * 4 + ks) * 64 + lane) * 8);
        acc[nt] = __builtin_amdgcn_mfma_f32_16x16x32_bf16(af[ks], bf, acc[nt],
                                                          0, 0, 0);
      }
    }
  }

  // ---- softmax over neighbors (rows): 4 local regs + shfl_xor(16,32) ----
  const float inv = 0.0883883476483184f;  // 1/sqrt(128)
  float resv[8];
#pragma unroll
  for (int nt = 0; nt < 8; ++nt) {
    float l0 = (acc[nt][0] + bg2v[nt]) * inv;
    float l1 = (acc[nt][1] + bg2v[nt]) * inv;
    float l2 = (acc[nt][2] + bg2v[nt]) * inv;
    float l3 = (acc[nt][3] + bg2v[nt]) * inv;
    float m4 = fmaxf(fmaxf(l0, l1), fmaxf(l2, l3));
    m4 = fmaxf(m4, __shfl_xor(m4, 16));
    m4 = fmaxf(m4, __shfl_xor(m4, 32));
    float e0 = expf(l0 - m4), e1 = expf(l1 - m4);
    float e2 = expf(l2 - m4), e3 = expf(l3 - m4);
    float s4 = e0 + e1 + e2 + e3;
    s4 += __shfl_xor(s4, 16);
    s4 += __shfl_xor(s4, 32);
    float rs = 1.f / s4;
    float a0 = e0 * rs, a1 = e1 * rs, a2 = e2 * rs, a3 = e3 * rs;
    size_t base = ((size_t)bn * 16 + g * 4) * 128 + nt * 16 + c;
    out_attn[base + 0 * 128] = a0;
    out_attn[base + 1 * 128] = a1;
    out_attn[base + 2 * 128] = a2;
    out_attn[base + 3 * 128] = a3;
    float r = 0.f;
    {
      float v0 = vv[((size_t)(b << 12) + idxr[0]) * 128 + nt * 16 + c];
      float v1 = vv[((size_t)(b << 12) + idxr[1]) * 128 + nt * 16 + c];
      float v2 = vv[((size_t)(b << 12) + idxr[2]) * 128 + nt * 16 + c];
      float v3 = vv[((size_t)(b << 12) + idxr[3]) * 128 + nt * 16 + c];
      r = fmaf(a0, v0 + PE[nt][0], r);
      r = fmaf(a1, v1 + PE[nt][1], r);
      r = fmaf(a2, v2 + PE[nt][2], r);
      r = fmaf(a3, v3 + PE[nt][3], r);
    }
    r += __shfl_xor(r, 16);
    r += __shfl_xor(r, 32);
    resv[nt] = r;
  }
  if (g == 0) {
#pragma unroll
    for (int nt = 0; nt < 8; ++nt)
      res_ws[(size_t)bn * 128 + nt * 16 + c] = resv[nt];
  }
}

// ---------------------------------------------------------------------------
// Epilogue: out_res = res @ W2 + b2 + pre   (16 points/block, mv16)
// ---------------------------------------------------------------------------
__global__ __launch_bounds__(128, 2) void epilogue_kernel(
    const float* __restrict__ res_ws, const float* __restrict__ W2,
    const float* __restrict__ b2, const float* __restrict__ pre,
    float* __restrict__ out_res) {
  const int t = threadIdx.x;
  const int g0 = blockIdx.x * 16;
  __shared__ __attribute__((aligned(16))) float buf[16 * 128];
#pragma unroll
  for (int p = 0; p < 16; ++p)
    buf[p * 128 + t] = res_ws[(size_t)(g0 + p) * 128 + t];
  __syncthreads();
  float acc[16];
  float bb = b2[t];
#pragma unroll
  for (int p = 0; p < 16; ++p)
    acc[p] = bb + pre[(size_t)(g0 + p) * 128 + t];
  mv16(W2 + t, buf, acc);
#pragma unroll
  for (int p = 0; p < 16; ++p)
    out_res[(size_t)(g0 + p) * 128 + t] = acc[p];
}

extern "C" void kernel_launch(void* const* d_in, const int* in_sizes, int n_in,
                              void* d_out, int out_size, void* d_ws,
                              size_t ws_size, hipStream_t stream) {
  const float* xyz = (const float*)d_in[0];
  const float* W0a = (const float*)d_in[1];
  const float* b0a = (const float*)d_in[2];
  const float* W0b = (const float*)d_in[3];
  const float* b0b = (const float*)d_in[4];
  const float* W1 = (const float*)d_in[5];
  const float* b1 = (const float*)d_in[6];
  const float* W2 = (const float*)d_in[7];
  const float* b2 = (const float*)d_in[8];
  const float* Wd1 = (const float*)d_in[9];
  const float* bd1 = (const float*)d_in[10];
  const float* Wd2 = (const float*)d_in[11];
  const float* bd2 = (const float*)d_in[12];
  const float* Wg1 = (const float*)d_in[13];
  const float* bg1 = (const float*)d_in[14];
  const float* Wg2 = (const float*)d_in[15];
  const float* bg2 = (const float*)d_in[16];
  const float* Wq = (const float*)d_in[17];
  const float* Wk = (const float*)d_in[18];
  const float* Wv = (const float*)d_in[19];

  char* ws = (char*)d_ws;
  int* knn = (int*)ws;                                  // 1 MB
  float* pre = (float*)(ws + (1 << 20));                // 8 MB
  float* qv = (float*)(ws + (9 << 20));                 // 8 MB
  float* kv = (float*)(ws + (17 << 20));                // 8 MB
  float* vv = (float*)(ws + (25 << 20));                // 8 MB
  float* res_ws = (float*)(ws + (33 << 20));            // 8 MB
  short* wsw = (short*)(ws + (41 << 20));               // 96 KB bf16 B-frags

  float* out_res = (float*)d_out;
  float* out_attn = out_res + (size_t)BN * DD;

  hipLaunchKernelGGL(swz_kernel, dim3(24), dim3(256), 0, stream, Wd2, Wg1, Wg2,
                     wsw);
  hipLaunchKernelGGL(knn_kernel, dim3(4096), dim3(256), 0, stream, xyz, knn);
  hipLaunchKernelGGL(point_mlp_kernel, dim3(1024), dim3(128), 0, stream, xyz,
                     W0a, b0a, W0b, b0b, W1, b1, Wq, Wk, Wv, pre, qv, kv, vv);
  hipLaunchKernelGGL(attn_mfma_kernel, dim3(4096), dim3(256), 0, stream, xyz,
                     knn, qv, kv, vv, wsw, Wd1, bd1, bd2, bg1, bg2, res_ws,
                     out_attn);
  hipLaunchKernelGGL(epilogue_kernel, dim3(1024), dim3(128), 0, stream, res_ws,
                     W2, b2, pre, out_res);
}